// Round 1
// baseline (210.184 us; speedup 1.0000x reference)
//
#include <hip/hip_runtime.h>

#define HEADS 8
#define DHEAD 40
#define SEQ   4096
#define BATCH 2
#define INNER 320
#define NBH   16
// softmax scale * log2(e), folded into Wq so p = exp2(s) is a single v_exp_f32
#define QSCALE ((float)(0.15811388300841897 * 1.4426950408889634))

typedef _Float16 f16;
typedef __attribute__((ext_vector_type(2)))  __fp16   fp16x2;  // cvt_pkrtz native type
typedef __attribute__((ext_vector_type(4)))  _Float16 half4;
typedef __attribute__((ext_vector_type(8)))  _Float16 half8;
typedef __attribute__((ext_vector_type(16))) float    f32x16;

#if __has_builtin(__builtin_amdgcn_exp2f)
#define EXP2F(x) __builtin_amdgcn_exp2f(x)
#else
#define EXP2F(x) exp2f(x)
#endif

union H8 { half8 h8; fp16x2 p2[4]; uint4 u4; };

// ---------------------------------------------------------------------------
// Convert fp32 inputs to f16 once: x -> xh [8192][320]; Wq|Wk|Wv -> wh
// [960][320] (Wq pre-scaled by QSCALE); Wout -> wouth [320][320].
// ---------------------------------------------------------------------------
#define XN4   (BATCH * SEQ * INNER / 4)   // 655360
#define WQKV4 (3 * INNER * INNER / 4)     // 76800
#define WOUT4 (INNER * INNER / 4)         // 25600
#define CONV_TOTAL (XN4 + WQKV4 + WOUT4)  // 757760

__global__ __launch_bounds__(256)
void convert_kernel(const float* __restrict__ x,
                    const float* __restrict__ Wq,
                    const float* __restrict__ Wk,
                    const float* __restrict__ Wv,
                    const float* __restrict__ Wout,
                    f16* __restrict__ xh, f16* __restrict__ wh,
                    f16* __restrict__ wouth)
{
    int i = blockIdx.x * 256 + threadIdx.x;
    if (i >= CONV_TOTAL) return;
    float4 v;
    f16* dst;
    float sc = 1.0f;
    if (i < XN4) {
        v = ((const float4*)x)[i];
        dst = xh + 4 * (size_t)i;
    } else if (i < XN4 + WQKV4) {
        int j = i - XN4;                       // float4 idx in concat [960][320]
        if (j < 25600)      { v = ((const float4*)Wq)[j]; sc = QSCALE; }
        else if (j < 51200) { v = ((const float4*)Wk)[j - 25600]; }
        else                { v = ((const float4*)Wv)[j - 51200]; }
        dst = wh + 4 * (size_t)j;
    } else {
        int j = i - XN4 - WQKV4;
        v = ((const float4*)Wout)[j];
        dst = wouth + 4 * (size_t)j;
    }
    H8 u;
    u.p2[0] = __builtin_amdgcn_cvt_pkrtz(v.x * sc, v.y * sc);
    u.p2[1] = __builtin_amdgcn_cvt_pkrtz(v.z * sc, v.w * sc);
    *(uint2*)dst = make_uint2(u.u4.x, u.u4.y);
}

// ---------------------------------------------------------------------------
// Merged QKV projection, fp16 MFMA. Each block: m-tile 64 x n-tile 192
// (64 cols of EACH of Wq, Wk, Wv) so the x A-tile is staged once for all
// three matrices. Grid (5 n, 128 m). Wave (mw, nw): 32 m-rows, 96 n
// (3 subtiles of 32). Epilogue: q,k scatter to [bh][S][40]; v subtiles
// (nw==1, t=1,2) transpose via LDS -> vt [bh][40][S] with keys
// block-permuted per 16-group ([0,2,1,3] on 4-blocks) to match attn's
// S^T-register P fragments.
// ---------------------------------------------------------------------------
#define QSTR 72

__global__ __launch_bounds__(256)
void qkv_gemm_kernel(const f16* __restrict__ xh, const f16* __restrict__ wh,
                     f16* __restrict__ q, f16* __restrict__ k,
                     f16* __restrict__ vt)
{
    __shared__ f16 lds[(64 + 192) * QSTR];   // As [64][72] + Bs [192][72] = 36864 B
    f16* As = lds;
    f16* Bs = lds + 64 * QSTR;

    const int tid = threadIdx.x;
    const int nb0 = blockIdx.x * 64;
    const int m0  = blockIdx.y * 64;
    const int wave = tid >> 6, lane = tid & 63, m = lane & 31, half = lane >> 5;
    const int mw = wave >> 1, nw = wave & 1;

    f32x16 acc[3];
    #pragma unroll
    for (int i = 0; i < 16; i++) { acc[0][i] = 0.f; acc[1][i] = 0.f; acc[2][i] = 0.f; }

    for (int k0 = 0; k0 < 320; k0 += 64) {
        __syncthreads();
        #pragma unroll
        for (int u = 0; u < 2; u++) {        // A: 64r x 64k = 512 uint4
            int idx = tid + 256 * u;
            int r = idx >> 3, c8 = idx & 7;
            *(uint4*)&As[r * QSTR + c8 * 8] =
                *(const uint4*)&xh[(size_t)(m0 + r) * 320 + k0 + c8 * 8];
        }
        #pragma unroll
        for (int u = 0; u < 6; u++) {        // B: 192r x 64k = 1536 uint4
            int idx = tid + 256 * u;
            int r = idx >> 3, c8 = idx & 7;
            int wr = (r >> 6) * 320 + nb0 + (r & 63);
            *(uint4*)&Bs[r * QSTR + c8 * 8] =
                *(const uint4*)&wh[(size_t)wr * 320 + k0 + c8 * 8];
        }
        __syncthreads();
        #pragma unroll
        for (int c = 0; c < 4; c++) {
            half8 a = *(const half8*)&As[(mw * 32 + m) * QSTR + c * 16 + half * 8];
            #pragma unroll
            for (int t = 0; t < 3; t++) {
                half8 bf = *(const half8*)&Bs[(nw * 96 + t * 32 + m) * QSTR + c * 16 + half * 8];
                acc[t] = __builtin_amdgcn_mfma_f32_32x32x16_f16(a, bf, acc[t], 0, 0, 0);
            }
        }
    }

    const int b = m0 >> 12, s0 = m0 & 4095;

    // q / k scatter (subtiles st = nw*3+t < 4)
    #pragma unroll
    for (int t = 0; t < 3; t++) {
        int st = nw * 3 + t;
        if (st < 4) {
            f16* dst = (st < 2) ? q : k;
            int col = nb0 + (st & 1) * 32 + m;
            int h  = (col * 205) >> 13;          // == col/40 for col<328
            int dd = col - h * 40;
            #pragma unroll
            for (int reg = 0; reg < 16; reg++) {
                int crow = 4 * half + (reg & 3) + 8 * (reg >> 2);
                int mg = m0 + mw * 32 + crow;
                int bb = mg >> 12, s = mg & 4095;
                dst[((size_t)(bb * 8 + h) * SEQ + s) * DHEAD + dd] = (f16)acc[t][reg];
            }
        }
    }

    // v transpose: subtiles st 4,5 (nw==1, t=1,2) -> Ct [64 vcol][72]
    __syncthreads();
    f16* Ct = lds;
    if (nw == 1) {
        #pragma unroll
        for (int t = 1; t < 3; t++) {
            int vr0 = (t - 1) * 32 + m;
            #pragma unroll
            for (int g = 0; g < 4; g++) {
                half4 hh;
                hh.x = (f16)acc[t][4 * g + 0]; hh.y = (f16)acc[t][4 * g + 1];
                hh.z = (f16)acc[t][4 * g + 2]; hh.w = (f16)acc[t][4 * g + 3];
                *(half4*)&Ct[vr0 * QSTR + mw * 32 + 8 * g + 4 * half] = hh;
            }
        }
    }
    __syncthreads();
    #pragma unroll
    for (int u = 0; u < 4; u++) {            // 64 rl x 16 c4 = 1024 uint2
        int idx = tid + 256 * u;
        int rl = idx >> 4, c4 = idx & 15;
        int col = nb0 + rl;
        int h  = (col * 205) >> 13;
        int dd = col - h * 40;
        int w4 = c4 & 3;
        int c4p = (c4 & ~3) | ((w4 == 1) ? 2 : (w4 == 2) ? 1 : w4);
        *(uint2*)&vt[((size_t)(b * 8 + h) * DHEAD + dd) * SEQ + s0 + c4p * 4] =
            *(const uint2*)&Ct[rl * QSTR + c4 * 4];
    }
}

// ---------------------------------------------------------------------------
// Flash attention, fp16 MFMA, P kept in registers (S^T trick).
// BARRIER-FREE main loop: K and V MFMA fragments are loaded DIRECTLY from
// global memory into registers (the frag addresses are the old LDS-fill
// addresses composed with the frag offsets; both layouts are 16B-aligned
// per lane). No LDS staging, no ds_reads, no bank conflicts, no
// __syncthreads in the loop -> the 4 waves run fully independently and
// MFMA / TRANS(exp) / VMEM overlap across waves.
//   - K frag c=2, half=1 reads cols 40..47 = start of the next key row:
//     finite garbage that multiplies qa[2]'s ZERO half -> contributes 0.
//   - Vt pad rows 40..63 synthesized per-lane: m==8 -> ones (row-sum row),
//     m>8 -> zero, m<8 -> real rows 32..39 (exec-masked load).
//   - K frags register-prefetched one 64-key tile ahead; V frags issued at
//     iteration top, consumed after S+exp (~300 cyc of latency cover).
//   - s_setprio(1) around MFMA clusters (T5).
// XCD swizzle: blocks blk%8==x map to bh {2x,2x+1}, so each XCD's L2 holds
// only 2 heads' K/V (~1.3 MB) instead of round-robin scattering all 16.
// Epilogue unchanged: key-half partials combine exactly in LDS f32.
// NOTE: launch_bounds (256,4) -> 128 unified VGPR+AGPR cap; budget ~118.
// ---------------------------------------------------------------------------
__global__ __launch_bounds__(256, 4)
void attn_kernel(const f16* __restrict__ q, const f16* __restrict__ k,
                 const f16* __restrict__ vt, f16* __restrict__ y)
{
    __shared__ float ldsf[64 * 66];              // epilogue combine, 16896 B

    const int tid = threadIdx.x;
    const int blk = blockIdx.x;
    const int xcd = blk & 7, slot = blk >> 3;    // XCD-aware swizzle
    const int bh = xcd * 2 + (slot >> 6), qt = slot & 63;
    const int b = bh >> 3, h = bh & 7;
    const int q0 = qt * 64;
    const int wave = tid >> 6, lane = tid & 63, m = lane & 31, half = lane >> 5;
    const int qs = wave >> 1, kh = wave & 1;

    half8 zero8, ones8;
    #pragma unroll
    for (int j = 0; j < 8; j++) { zero8[j] = (f16)0.0f; ones8[j] = (f16)1.0f; }

    // Q B-fragments in registers (d 40..47 -> 0)
    half8 qa[3];
    {
        const f16* qb = q + ((size_t)bh * SEQ + q0 + qs * 32 + m) * DHEAD;
        qa[0] = *(const half8*)&qb[half * 8];
        qa[1] = *(const half8*)&qb[16 + half * 8];
        qa[2] = (half == 1) ? zero8 : *(const half8*)&qb[32];
    }

    f32x16 O[2];
    #pragma unroll
    for (int i = 0; i < 16; i++) { O[0][i] = 0.f; O[1][i] = 0.f; }

    const f16* kb = k  + (size_t)bh * SEQ * DHEAD;   // [s][40]
    const f16* vb = vt + (size_t)bh * DHEAD * SEQ;   // [d][SEQ], keys perm'd

    // per-lane fragment base pointers (advance by j0 inside the loop)
    const f16* kl  = kb + (size_t)(kh * 32 + m) * DHEAD + half * 8;
    const f16* v0l = vb + (size_t)m * SEQ + kh * 32 + half * 8;
    const f16* v1l = vb + (size_t)(32 + (m & 7)) * SEQ + kh * 32 + half * 8;

    // prefetch K frags for tile 0
    half8 kf0 = *(const half8*)(kl);
    half8 kf1 = *(const half8*)(kl + 16);
    half8 kf2 = *(const half8*)(kl + 32);   // half==1: finite garbage x qa2==0

    for (int j0 = 0; j0 < SEQ; j0 += 64) {
        // V frag loads for THIS tile: in flight during S MFMAs + exp
        const f16* v0p = v0l + j0;
        const f16* v1p = v1l + j0;
        half8 va00 = *(const half8*)(v0p);
        half8 va01 = *(const half8*)(v0p + 16);
        half8 va10 = zero8, va11 = zero8;
        if (m < 8) {                                 // rows 32..39 only
            va10 = *(const half8*)(v1p);
            va11 = *(const half8*)(v1p + 16);
        }

        // ---- S^T = K . Q^T for keys kh*32..+31, queries qs*32..+31
        f32x16 S;
        #pragma unroll
        for (int i = 0; i < 16; i++) S[i] = 0.f;
        __builtin_amdgcn_s_setprio(1);
        S = __builtin_amdgcn_mfma_f32_32x32x16_f16(kf0, qa[0], S, 0, 0, 0);
        S = __builtin_amdgcn_mfma_f32_32x32x16_f16(kf1, qa[1], S, 0, 0, 0);
        S = __builtin_amdgcn_mfma_f32_32x32x16_f16(kf2, qa[2], S, 0, 0, 0);
        __builtin_amdgcn_s_setprio(0);

        // prefetch next tile's K frags (in flight during exp + PV)
        if (j0 + 64 < SEQ) {
            const f16* kp = kl + (size_t)(j0 + 64) * DHEAD;
            kf0 = *(const half8*)(kp);
            kf1 = *(const half8*)(kp + 16);
            kf2 = *(const half8*)(kp + 32);
        }

        // ---- p = exp2(s): raw v_exp_f32 + packed RTZ cvt (bias cancels in ratio)
        H8 p0u, p1u;
        #pragma unroll
        for (int g = 0; g < 4; g++) {
            p0u.p2[g] = __builtin_amdgcn_cvt_pkrtz(EXP2F(S[2 * g]),     EXP2F(S[2 * g + 1]));
            p1u.p2[g] = __builtin_amdgcn_cvt_pkrtz(EXP2F(S[8 + 2 * g]), EXP2F(S[9 + 2 * g]));
        }

        // ---- O += P . V  (lane m==8 carries the ones-row -> row sums)
        half8 w0 = (m == 8) ? ones8 : va10;
        half8 w1 = (m == 8) ? ones8 : va11;
        __builtin_amdgcn_s_setprio(1);
        O[0] = __builtin_amdgcn_mfma_f32_32x32x16_f16(p0u.h8, va00, O[0], 0, 0, 0);
        O[1] = __builtin_amdgcn_mfma_f32_32x32x16_f16(p0u.h8, w0,   O[1], 0, 0, 0);
        O[0] = __builtin_amdgcn_mfma_f32_32x32x16_f16(p1u.h8, va01, O[0], 0, 0, 0);
        O[1] = __builtin_amdgcn_mfma_f32_32x32x16_f16(p1u.h8, w1,   O[1], 0, 0, 0);
        __builtin_amdgcn_s_setprio(0);
    }

    // ---- combine key-halves (exact: unnormalized sums), normalize, store y
    if (kh == 1) {
        #pragma unroll
        for (int t = 0; t < 2; t++)
            #pragma unroll
            for (int reg = 0; reg < 16; reg++) {
                int row = 4 * half + (reg & 3) + 8 * (reg >> 2);
                ldsf[(qs * 32 + row) * 66 + t * 32 + m] = O[t][reg];
            }
    }
    __syncthreads();
    if (kh == 0) {
        #pragma unroll
        for (int t = 0; t < 2; t++)
            #pragma unroll
            for (int reg = 0; reg < 16; reg++) {
                int row = 4 * half + (reg & 3) + 8 * (reg >> 2);
                O[t][reg] += ldsf[(qs * 32 + row) * 66 + t * 32 + m];
            }
        #pragma unroll
        for (int reg = 0; reg < 16; reg++) {
            float l = __shfl(O[1][reg], 8 + 32 * half, 64);
            float rinv = 1.0f / l;
            int row = 4 * half + (reg & 3) + 8 * (reg >> 2);
            f16* yr = y + ((size_t)b * SEQ + q0 + qs * 32 + row) * INNER + h * DHEAD;
            yr[m] = (f16)(O[0][reg] * rinv);                 // d 0..31
            if (m < 8) yr[32 + m] = (f16)(O[1][reg] * rinv); // d 32..39
        }
    }
}

// ---------------------------------------------------------------------------
// Output projection, fp16 MFMA: out = y @ Wout^T + bout, fp32 out.
// All-f16 staging (y and pre-converted wouth). Grid: x = n (5), y = m (64).
// ---------------------------------------------------------------------------
#define ASTR 72

__global__ __launch_bounds__(256)
void out_proj_kernel(const f16* __restrict__ y, const f16* __restrict__ wouth,
                     const float* __restrict__ bout, float* __restrict__ out)
{
    __shared__ f16 lds[(128 + 64) * ASTR];
    f16* As = lds;
    f16* Bs = lds + 128 * ASTR;

    const int tid = threadIdx.x;
    const int m0 = blockIdx.y * 128;
    const int n0 = blockIdx.x * 64;
    const int wave = tid >> 6, lane = tid & 63, m = lane & 31, half = lane >> 5;

    f32x16 acc[2];
    #pragma unroll
    for (int i = 0; i < 16; i++) { acc[0][i] = 0.f; acc[1][i] = 0.f; }

    for (int k0 = 0; k0 < 320; k0 += 64) {
        __syncthreads();
        #pragma unroll
        for (int u = 0; u < 4; u++) {
            int idx = tid + 256 * u;
            int r = idx >> 3, c8 = idx & 7;
            *(uint4*)&As[r * ASTR + c8 * 8] =
                *(const uint4*)&y[(size_t)(m0 + r) * 320 + k0 + c8 * 8];
        }
        #pragma unroll
        for (int u = 0; u < 2; u++) {
            int idx = tid + 256 * u;
            int r = idx >> 3, c8 = idx & 7;
            *(uint4*)&Bs[r * ASTR + c8 * 8] =
                *(const uint4*)&wouth[(size_t)(n0 + r) * 320 + k0 + c8 * 8];
        }
        __syncthreads();
        #pragma unroll
        for (int c = 0; c < 4; c++) {
            half8 a  = *(const half8*)&As[(wave * 32 + m) * ASTR + c * 16 + half * 8];
            half8 b0 = *(const half8*)&Bs[m * ASTR + c * 16 + half * 8];
            half8 b1 = *(const half8*)&Bs[(32 + m) * ASTR + c * 16 + half * 8];
            acc[0] = __builtin_amdgcn_mfma_f32_32x32x16_f16(a, b0, acc[0], 0, 0, 0);
            acc[1] = __builtin_amdgcn_mfma_f32_32x32x16_f16(a, b1, acc[1], 0, 0, 0);
        }
    }

    #pragma unroll
    for (int nt = 0; nt < 2; nt++) {
        int n = n0 + nt * 32 + m;
        float bias = bout[n];
        #pragma unroll
        for (int reg = 0; reg < 16; reg++) {
            int crow = 4 * half + (reg & 3) + 8 * (reg >> 2);
            out[(size_t)(m0 + wave * 32 + crow) * 320 + n] = acc[nt][reg] + bias;
        }
    }
}

// ---------------------------------------------------------------------------
extern "C" void kernel_launch(void* const* d_in, const int* in_sizes, int n_in,
                              void* d_out, int out_size, void* d_ws, size_t ws_size,
                              hipStream_t stream)
{
    const float* x    = (const float*)d_in[0];
    const float* Wq   = (const float*)d_in[1];
    const float* Wk   = (const float*)d_in[2];
    const float* Wv   = (const float*)d_in[3];
    const float* Wout = (const float*)d_in[4];
    const float* bout = (const float*)d_in[5];
    float* out = (float*)d_out;

    unsigned char* ws = (unsigned char*)d_ws;
    f16* xh    = (f16*)(ws);                  //  5,242,880 B
    f16* wh    = (f16*)(ws +  5242880);       //    614,400 B
    f16* wouth = (f16*)(ws +  5857280);       //    204,800 B
    f16* qd    = (f16*)(ws +  6062080);       //  5,242,880 B
    f16* kd    = (f16*)(ws + 11304960);       //  5,242,880 B
    f16* vtd   = (f16*)(ws + 16547840);       //  5,242,880 B
    f16* yd    = (f16*)(ws + 21790720);       //  5,242,880 B

    convert_kernel <<<2960,         256, 0, stream>>>(x, Wq, Wk, Wv, Wout, xh, wh, wouth);
    qkv_gemm_kernel<<<dim3(5, 128), 256, 0, stream>>>(xh, wh, qd, kd, vtd);
    attn_kernel    <<<1024,         256, 0, stream>>>(qd, kd, vtd, yd);
    out_proj_kernel<<<dim3(5, 64),  256, 0, stream>>>(yd, wouth, bout, out);
}

// Round 2
// 162.314 us; speedup vs baseline: 1.2949x; 1.2949x over previous
//
#include <hip/hip_runtime.h>

#define HEADS 8
#define DHEAD 40
#define SEQ   4096
#define BATCH 2
#define INNER 320
#define NBH   16
// softmax scale * log2(e), folded into Wq so p = exp2(s) is a single v_exp_f32
#define QSCALE ((float)(0.15811388300841897 * 1.4426950408889634))

typedef _Float16 f16;
typedef __attribute__((ext_vector_type(2)))  __fp16   fp16x2;  // cvt_pkrtz native type
typedef __attribute__((ext_vector_type(4)))  _Float16 half4;
typedef __attribute__((ext_vector_type(8)))  _Float16 half8;
typedef __attribute__((ext_vector_type(16))) float    f32x16;

#if __has_builtin(__builtin_amdgcn_exp2f)
#define EXP2F(x) __builtin_amdgcn_exp2f(x)
#else
#define EXP2F(x) exp2f(x)
#endif

union H8 { half8 h8; fp16x2 p2[4]; uint4 u4; };

// ---------------------------------------------------------------------------
// Convert fp32 inputs to f16 once: x -> xh [8192][320]; Wq|Wk|Wv -> wh
// [960][320] (Wq pre-scaled by QSCALE); Wout -> wouth [320][320].
// ---------------------------------------------------------------------------
#define XN4   (BATCH * SEQ * INNER / 4)   // 655360
#define WQKV4 (3 * INNER * INNER / 4)     // 76800
#define WOUT4 (INNER * INNER / 4)         // 25600
#define CONV_TOTAL (XN4 + WQKV4 + WOUT4)  // 757760

__global__ __launch_bounds__(256)
void convert_kernel(const float* __restrict__ x,
                    const float* __restrict__ Wq,
                    const float* __restrict__ Wk,
                    const float* __restrict__ Wv,
                    const float* __restrict__ Wout,
                    f16* __restrict__ xh, f16* __restrict__ wh,
                    f16* __restrict__ wouth)
{
    int i = blockIdx.x * 256 + threadIdx.x;
    if (i >= CONV_TOTAL) return;
    float4 v;
    f16* dst;
    float sc = 1.0f;
    if (i < XN4) {
        v = ((const float4*)x)[i];
        dst = xh + 4 * (size_t)i;
    } else if (i < XN4 + WQKV4) {
        int j = i - XN4;                       // float4 idx in concat [960][320]
        if (j < 25600)      { v = ((const float4*)Wq)[j]; sc = QSCALE; }
        else if (j < 51200) { v = ((const float4*)Wk)[j - 25600]; }
        else                { v = ((const float4*)Wv)[j - 51200]; }
        dst = wh + 4 * (size_t)j;
    } else {
        int j = i - XN4 - WQKV4;
        v = ((const float4*)Wout)[j];
        dst = wouth + 4 * (size_t)j;
    }
    H8 u;
    u.p2[0] = __builtin_amdgcn_cvt_pkrtz(v.x * sc, v.y * sc);
    u.p2[1] = __builtin_amdgcn_cvt_pkrtz(v.z * sc, v.w * sc);
    *(uint2*)dst = make_uint2(u.u4.x, u.u4.y);
}

// ---------------------------------------------------------------------------
// Merged QKV projection, fp16 MFMA. (unchanged from the 163us baseline)
// ---------------------------------------------------------------------------
#define QSTR 72

__global__ __launch_bounds__(256)
void qkv_gemm_kernel(const f16* __restrict__ xh, const f16* __restrict__ wh,
                     f16* __restrict__ q, f16* __restrict__ k,
                     f16* __restrict__ vt)
{
    __shared__ f16 lds[(64 + 192) * QSTR];   // As [64][72] + Bs [192][72] = 36864 B
    f16* As = lds;
    f16* Bs = lds + 64 * QSTR;

    const int tid = threadIdx.x;
    const int nb0 = blockIdx.x * 64;
    const int m0  = blockIdx.y * 64;
    const int wave = tid >> 6, lane = tid & 63, m = lane & 31, half = lane >> 5;
    const int mw = wave >> 1, nw = wave & 1;

    f32x16 acc[3];
    #pragma unroll
    for (int i = 0; i < 16; i++) { acc[0][i] = 0.f; acc[1][i] = 0.f; acc[2][i] = 0.f; }

    for (int k0 = 0; k0 < 320; k0 += 64) {
        __syncthreads();
        #pragma unroll
        for (int u = 0; u < 2; u++) {        // A: 64r x 64k = 512 uint4
            int idx = tid + 256 * u;
            int r = idx >> 3, c8 = idx & 7;
            *(uint4*)&As[r * QSTR + c8 * 8] =
                *(const uint4*)&xh[(size_t)(m0 + r) * 320 + k0 + c8 * 8];
        }
        #pragma unroll
        for (int u = 0; u < 6; u++) {        // B: 192r x 64k = 1536 uint4
            int idx = tid + 256 * u;
            int r = idx >> 3, c8 = idx & 7;
            int wr = (r >> 6) * 320 + nb0 + (r & 63);
            *(uint4*)&Bs[r * QSTR + c8 * 8] =
                *(const uint4*)&wh[(size_t)wr * 320 + k0 + c8 * 8];
        }
        __syncthreads();
        #pragma unroll
        for (int c = 0; c < 4; c++) {
            half8 a = *(const half8*)&As[(mw * 32 + m) * QSTR + c * 16 + half * 8];
            #pragma unroll
            for (int t = 0; t < 3; t++) {
                half8 bf = *(const half8*)&Bs[(nw * 96 + t * 32 + m) * QSTR + c * 16 + half * 8];
                acc[t] = __builtin_amdgcn_mfma_f32_32x32x16_f16(a, bf, acc[t], 0, 0, 0);
            }
        }
    }

    const int b = m0 >> 12, s0 = m0 & 4095;

    // q / k scatter (subtiles st = nw*3+t < 4)
    #pragma unroll
    for (int t = 0; t < 3; t++) {
        int st = nw * 3 + t;
        if (st < 4) {
            f16* dst = (st < 2) ? q : k;
            int col = nb0 + (st & 1) * 32 + m;
            int h  = (col * 205) >> 13;          // == col/40 for col<328
            int dd = col - h * 40;
            #pragma unroll
            for (int reg = 0; reg < 16; reg++) {
                int crow = 4 * half + (reg & 3) + 8 * (reg >> 2);
                int mg = m0 + mw * 32 + crow;
                int bb = mg >> 12, s = mg & 4095;
                dst[((size_t)(bb * 8 + h) * SEQ + s) * DHEAD + dd] = (f16)acc[t][reg];
            }
        }
    }

    // v transpose: subtiles st 4,5 (nw==1, t=1,2) -> Ct [64 vcol][72]
    __syncthreads();
    f16* Ct = lds;
    if (nw == 1) {
        #pragma unroll
        for (int t = 1; t < 3; t++) {
            int vr0 = (t - 1) * 32 + m;
            #pragma unroll
            for (int g = 0; g < 4; g++) {
                half4 hh;
                hh.x = (f16)acc[t][4 * g + 0]; hh.y = (f16)acc[t][4 * g + 1];
                hh.z = (f16)acc[t][4 * g + 2]; hh.w = (f16)acc[t][4 * g + 3];
                *(half4*)&Ct[vr0 * QSTR + mw * 32 + 8 * g + 4 * half] = hh;
            }
        }
    }
    __syncthreads();
    #pragma unroll
    for (int u = 0; u < 4; u++) {            // 64 rl x 16 c4 = 1024 uint2
        int idx = tid + 256 * u;
        int rl = idx >> 4, c4 = idx & 15;
        int col = nb0 + rl;
        int h  = (col * 205) >> 13;
        int dd = col - h * 40;
        int w4 = c4 & 3;
        int c4p = (c4 & ~3) | ((w4 == 1) ? 2 : (w4 == 2) ? 1 : w4);
        *(uint2*)&vt[((size_t)(b * 8 + h) * DHEAD + dd) * SEQ + s0 + c4p * 4] =
            *(const uint2*)&Ct[rl * QSTR + c4 * 4];
    }
}

// ---------------------------------------------------------------------------
// Flash attention, fp16 MFMA, P in registers (S^T trick).
// v2 structure: q-tile 128 per block, 4 waves = (qpair, key-half).
// Each wave computes 64 q-rows x 32 keys, so every K/V fragment read from
// LDS feeds 2 MFMAs (K,V frags are independent of the q index) -> LDS read
// traffic per unit work halves vs the 64-row version; staging writes also
// amortize 2x. LDS K/V tiles are double-buffered (one __syncthreads per
// iter, WAR-safe by buffer alternation) and XOR-swizzled:
//   row stride 64 halves (128B), 16B chunk c stored at 8*(c ^ (row&7))
// -> ds_read_b128 spreads over all 32 banks (was 2.6M conflict cycles).
// Pads written once per buffer: K logical chunk 5 = 0 (covers q-cols 40..47),
// V rows 40..63 (row 40 = ones for row-sums, rest 0) at swizzled slots.
// S accumulators init from a constant zero tile (saves 32 v_mov/wave/iter).
// Epilogue: key-half partials combine exactly in LDS f32 (region unioned
// with the staging buffers), then normalize by the ones-row sum.
// ---------------------------------------------------------------------------
__global__ __launch_bounds__(256, 2)
void attn_kernel(const f16* __restrict__ q, const f16* __restrict__ k,
                 const f16* __restrict__ vt, f16* __restrict__ y)
{
    // union: staging 2 x (K 8192B + V 8192B) = 32768B  |  epilogue f32 [128][66] = 33792B
    __shared__ __align__(16) unsigned char ldsbuf[33792];
    f16*   ldsh = (f16*)ldsbuf;
    float* ldsf = (float*)ldsbuf;

    const int tid = threadIdx.x;
    const int blk = blockIdx.x;
    const int xcd = blk & 7, slot = blk >> 3;        // XCD swizzle: 2 bh per XCD
    const int bh = xcd * 2 + (slot >> 5), qt = slot & 31;
    const int b = bh >> 3, h = bh & 7;
    const int q0 = qt * 128;
    const int wave = tid >> 6, lane = tid & 63, m = lane & 31, half = lane >> 5;
    const int qp = wave >> 1, kh = wave & 1;
    const int x7 = m & 7;

    // ---- one-time pads (swizzled slots, both buffers)
    if (tid < 128) {                                  // K logical chunk 5 = 0
        int bsel = tid >> 6, r = tid & 63;
        *(uint4*)&ldsh[bsel * 8192 + r * 64 + 8 * (5 ^ (r & 7))] = make_uint4(0, 0, 0, 0);
    }
    #pragma unroll
    for (int u = 0; u < 2; u++) {                     // V rows 40..63
        int idx = tid + 256 * u;
        if (idx < 384) {
            int bsel = (idx >= 192) ? 1 : 0;
            int j = idx - bsel * 192;
            int r = 40 + (j >> 3), c = j & 7;
            uint4 val = (r == 40) ? make_uint4(0x3C003C00u, 0x3C003C00u, 0x3C003C00u, 0x3C003C00u)
                                  : make_uint4(0, 0, 0, 0);
            *(uint4*)&ldsh[bsel * 8192 + 4096 + r * 64 + 8 * (c ^ (r & 7))] = val;
        }
    }

    half8 zero8;
    #pragma unroll
    for (int j = 0; j < 8; j++) zero8[j] = (f16)0.0f;

    // ---- Q B-fragments for both q-subtiles (d 40..47 -> 0)
    half8 qa[2][3];
    {
        const f16* qb = q + ((size_t)bh * SEQ + q0 + qp * 64 + m) * DHEAD;
        #pragma unroll
        for (int a = 0; a < 2; a++) {
            const f16* qr = qb + a * 32 * DHEAD;
            qa[a][0] = *(const half8*)&qr[half * 8];
            qa[a][1] = *(const half8*)&qr[16 + half * 8];
            qa[a][2] = (half == 1) ? zero8 : *(const half8*)&qr[32];
        }
    }

    f32x16 O[4];                     // [a*2+t]: a = q-subtile, t = d 0..31 / 32..63
    #pragma unroll
    for (int i = 0; i < 16; i++) { O[0][i] = 0.f; O[1][i] = 0.f; O[2][i] = 0.f; O[3][i] = 0.f; }
    f32x16 Zc;                       // constant zero accumulator for S init
    #pragma unroll
    for (int i = 0; i < 16; i++) Zc[i] = 0.f;

    const f16* kb = k  + (size_t)bh * SEQ * DHEAD;   // [s][40]
    const f16* vb = vt + (size_t)bh * DHEAD * SEQ;   // [d][SEQ], keys perm'd

    // ---- staging indices (constant): K 320 uint4 (row=idx/5,c=idx%5),
    //      V 320 uint4 (row=idx>>3,c=idx&7); thread t does idx t (+256 if t<64)
    const int krow0 = (tid * 205) >> 10,         kc0 = tid - krow0 * 5;
    const int krow1 = ((256 + tid) * 205) >> 10, kc1 = (256 + tid) - krow1 * 5;
    const int vrow0 = tid >> 3,        vc0 = tid & 7;
    const int vrow1 = (256 + tid) >> 3;              // vc1 == vc0
    const bool lo = (tid < 64);
    const int kdst0 = krow0 * 64 + 8 * (kc0 ^ (krow0 & 7));
    const int kdst1 = krow1 * 64 + 8 * (kc1 ^ (krow1 & 7));
    const int vdst0 = 4096 + vrow0 * 64 + 8 * (vc0 ^ (vrow0 & 7));
    const int vdst1 = 4096 + vrow1 * 64 + 8 * (vc0 ^ (vrow1 & 7));

    // prefetch tile 0 into registers
    uint4 sk0, sk1, sv0, sv1;
    sk0 = *(const uint4*)&kb[krow0 * DHEAD + kc0 * 8];
    sv0 = *(const uint4*)&vb[(size_t)vrow0 * SEQ + vc0 * 8];
    if (lo) {
        sk1 = *(const uint4*)&kb[krow1 * DHEAD + kc1 * 8];
        sv1 = *(const uint4*)&vb[(size_t)vrow1 * SEQ + vc0 * 8];
    }

    for (int j0 = 0; j0 < SEQ; j0 += 64) {
        const int stg = ((j0 >> 6) & 1) * 8192;
        // write staged regs -> LDS[buf]
        *(uint4*)&ldsh[stg + kdst0] = sk0;
        *(uint4*)&ldsh[stg + vdst0] = sv0;
        if (lo) {
            *(uint4*)&ldsh[stg + kdst1] = sk1;
            *(uint4*)&ldsh[stg + vdst1] = sv1;
        }
        __syncthreads();

        // prefetch next tile (lands during this tile's compute)
        if (j0 + 64 < SEQ) {
            const int jn = j0 + 64;
            sk0 = *(const uint4*)&kb[(jn + krow0) * DHEAD + kc0 * 8];
            sv0 = *(const uint4*)&vb[(size_t)vrow0 * SEQ + jn + vc0 * 8];
            if (lo) {
                sk1 = *(const uint4*)&kb[(jn + krow1) * DHEAD + kc1 * 8];
                sv1 = *(const uint4*)&vb[(size_t)vrow1 * SEQ + jn + vc0 * 8];
            }
        }

        const f16* Kb = &ldsh[stg];
        const f16* Vb = &ldsh[stg + 4096];

        // ---- S^T = K . Q^T, both q-subtiles share the K frags
        half8 kf[3];
        #pragma unroll
        for (int c = 0; c < 3; c++)
            kf[c] = *(const half8*)&Kb[(kh * 32 + m) * 64 + 8 * ((2 * c + half) ^ x7)];

        f32x16 Sa, Sb;
        __builtin_amdgcn_s_setprio(1);
        Sa = __builtin_amdgcn_mfma_f32_32x32x16_f16(kf[0], qa[0][0], Zc, 0, 0, 0);
        Sb = __builtin_amdgcn_mfma_f32_32x32x16_f16(kf[0], qa[1][0], Zc, 0, 0, 0);
        Sa = __builtin_amdgcn_mfma_f32_32x32x16_f16(kf[1], qa[0][1], Sa, 0, 0, 0);
        Sb = __builtin_amdgcn_mfma_f32_32x32x16_f16(kf[1], qa[1][1], Sb, 0, 0, 0);
        Sa = __builtin_amdgcn_mfma_f32_32x32x16_f16(kf[2], qa[0][2], Sa, 0, 0, 0);
        Sb = __builtin_amdgcn_mfma_f32_32x32x16_f16(kf[2], qa[1][2], Sb, 0, 0, 0);
        __builtin_amdgcn_s_setprio(0);

        // ---- V frags (shared by both q-subtiles)
        half8 vf[2][2];
        #pragma unroll
        for (int c = 0; c < 2; c++) {
            vf[c][0] = *(const half8*)&Vb[m * 64        + 8 * ((4 * kh + 2 * c + half) ^ x7)];
            vf[c][1] = *(const half8*)&Vb[(32 + m) * 64 + 8 * ((4 * kh + 2 * c + half) ^ x7)];
        }

        // ---- p = exp2(s), packed RTZ cvt (bias cancels in ratio)
        H8 pa0, pa1, pb0, pb1;
        #pragma unroll
        for (int g = 0; g < 4; g++) {
            pa0.p2[g] = __builtin_amdgcn_cvt_pkrtz(EXP2F(Sa[2 * g]),     EXP2F(Sa[2 * g + 1]));
            pa1.p2[g] = __builtin_amdgcn_cvt_pkrtz(EXP2F(Sa[8 + 2 * g]), EXP2F(Sa[9 + 2 * g]));
            pb0.p2[g] = __builtin_amdgcn_cvt_pkrtz(EXP2F(Sb[2 * g]),     EXP2F(Sb[2 * g + 1]));
            pb1.p2[g] = __builtin_amdgcn_cvt_pkrtz(EXP2F(Sb[8 + 2 * g]), EXP2F(Sb[9 + 2 * g]));
        }

        // ---- O += P . V  (ones-row at d-row 40 accumulates row sums)
        __builtin_amdgcn_s_setprio(1);
        O[0] = __builtin_amdgcn_mfma_f32_32x32x16_f16(pa0.h8, vf[0][0], O[0], 0, 0, 0);
        O[1] = __builtin_amdgcn_mfma_f32_32x32x16_f16(pa0.h8, vf[0][1], O[1], 0, 0, 0);
        O[2] = __builtin_amdgcn_mfma_f32_32x32x16_f16(pb0.h8, vf[0][0], O[2], 0, 0, 0);
        O[3] = __builtin_amdgcn_mfma_f32_32x32x16_f16(pb0.h8, vf[0][1], O[3], 0, 0, 0);
        O[0] = __builtin_amdgcn_mfma_f32_32x32x16_f16(pa1.h8, vf[1][0], O[0], 0, 0, 0);
        O[1] = __builtin_amdgcn_mfma_f32_32x32x16_f16(pa1.h8, vf[1][1], O[1], 0, 0, 0);
        O[2] = __builtin_amdgcn_mfma_f32_32x32x16_f16(pb1.h8, vf[1][0], O[2], 0, 0, 0);
        O[3] = __builtin_amdgcn_mfma_f32_32x32x16_f16(pb1.h8, vf[1][1], O[3], 0, 0, 0);
        __builtin_amdgcn_s_setprio(0);
    }

    // ---- combine key-halves (exact: unnormalized sums), normalize, store y
    __syncthreads();
    if (kh == 1) {
        #pragma unroll
        for (int a = 0; a < 2; a++)
            #pragma unroll
            for (int t = 0; t < 2; t++)
                #pragma unroll
                for (int reg = 0; reg < 16; reg++) {
                    int row = 4 * half + (reg & 3) + 8 * (reg >> 2);
                    ldsf[(qp * 64 + a * 32 + row) * 66 + t * 32 + m] = O[a * 2 + t][reg];
                }
    }
    __syncthreads();
    if (kh == 0) {
        #pragma unroll
        for (int a = 0; a < 2; a++) {
            #pragma unroll
            for (int t = 0; t < 2; t++)
                #pragma unroll
                for (int reg = 0; reg < 16; reg++) {
                    int row = 4 * half + (reg & 3) + 8 * (reg >> 2);
                    O[a * 2 + t][reg] += ldsf[(qp * 64 + a * 32 + row) * 66 + t * 32 + m];
                }
            #pragma unroll
            for (int reg = 0; reg < 16; reg++) {
                float l = __shfl(O[a * 2 + 1][reg], 8 + 32 * half, 64);
                float rinv = 1.0f / l;
                int row = 4 * half + (reg & 3) + 8 * (reg >> 2);
                f16* yr = y + ((size_t)b * SEQ + q0 + qp * 64 + a * 32 + row) * INNER + h * DHEAD;
                yr[m] = (f16)(O[a * 2 + 0][reg] * rinv);                 // d 0..31
                if (m < 8) yr[32 + m] = (f16)(O[a * 2 + 1][reg] * rinv); // d 32..39
            }
        }
    }
}

// ---------------------------------------------------------------------------
// Output projection, fp16 MFMA: out = y @ Wout^T + bout, fp32 out.
// ---------------------------------------------------------------------------
#define ASTR 72

__global__ __launch_bounds__(256)
void out_proj_kernel(const f16* __restrict__ y, const f16* __restrict__ wouth,
                     const float* __restrict__ bout, float* __restrict__ out)
{
    __shared__ f16 lds[(128 + 64) * ASTR];
    f16* As = lds;
    f16* Bs = lds + 128 * ASTR;

    const int tid = threadIdx.x;
    const int m0 = blockIdx.y * 128;
    const int n0 = blockIdx.x * 64;
    const int wave = tid >> 6, lane = tid & 63, m = lane & 31, half = lane >> 5;

    f32x16 acc[2];
    #pragma unroll
    for (int i = 0; i < 16; i++) { acc[0][i] = 0.f; acc[1][i] = 0.f; }

    for (int k0 = 0; k0 < 320; k0 += 64) {
        __syncthreads();
        #pragma unroll
        for (int u = 0; u < 4; u++) {
            int idx = tid + 256 * u;
            int r = idx >> 3, c8 = idx & 7;
            *(uint4*)&As[r * ASTR + c8 * 8] =
                *(const uint4*)&y[(size_t)(m0 + r) * 320 + k0 + c8 * 8];
        }
        #pragma unroll
        for (int u = 0; u < 2; u++) {
            int idx = tid + 256 * u;
            int r = idx >> 3, c8 = idx & 7;
            *(uint4*)&Bs[r * ASTR + c8 * 8] =
                *(const uint4*)&wouth[(size_t)(n0 + r) * 320 + k0 + c8 * 8];
        }
        __syncthreads();
        #pragma unroll
        for (int c = 0; c < 4; c++) {
            half8 a  = *(const half8*)&As[(wave * 32 + m) * ASTR + c * 16 + half * 8];
            half8 b0 = *(const half8*)&Bs[m * ASTR + c * 16 + half * 8];
            half8 b1 = *(const half8*)&Bs[(32 + m) * ASTR + c * 16 + half * 8];
            acc[0] = __builtin_amdgcn_mfma_f32_32x32x16_f16(a, b0, acc[0], 0, 0, 0);
            acc[1] = __builtin_amdgcn_mfma_f32_32x32x16_f16(a, b1, acc[1], 0, 0, 0);
        }
    }

    #pragma unroll
    for (int nt = 0; nt < 2; nt++) {
        int n = n0 + nt * 32 + m;
        float bias = bout[n];
        #pragma unroll
        for (int reg = 0; reg < 16; reg++) {
            int crow = 4 * half + (reg & 3) + 8 * (reg >> 2);
            out[(size_t)(m0 + wave * 32 + crow) * 320 + n] = acc[nt][reg] + bias;
        }
    }
}

// ---------------------------------------------------------------------------
extern "C" void kernel_launch(void* const* d_in, const int* in_sizes, int n_in,
                              void* d_out, int out_size, void* d_ws, size_t ws_size,
                              hipStream_t stream)
{
    const float* x    = (const float*)d_in[0];
    const float* Wq   = (const float*)d_in[1];
    const float* Wk   = (const float*)d_in[2];
    const float* Wv   = (const float*)d_in[3];
    const float* Wout = (const float*)d_in[4];
    const float* bout = (const float*)d_in[5];
    float* out = (float*)d_out;

    unsigned char* ws = (unsigned char*)d_ws;
    f16* xh    = (f16*)(ws);                  //  5,242,880 B
    f16* wh    = (f16*)(ws +  5242880);       //    614,400 B
    f16* wouth = (f16*)(ws +  5857280);       //    204,800 B
    f16* qd    = (f16*)(ws +  6062080);       //  5,242,880 B
    f16* kd    = (f16*)(ws + 11304960);       //  5,242,880 B
    f16* vtd   = (f16*)(ws + 16547840);       //  5,242,880 B
    f16* yd    = (f16*)(ws + 21790720);       //  5,242,880 B

    convert_kernel <<<2960,         256, 0, stream>>>(x, Wq, Wk, Wv, Wout, xh, wh, wouth);
    qkv_gemm_kernel<<<dim3(5, 128), 256, 0, stream>>>(xh, wh, qd, kd, vtd);
    attn_kernel    <<<512,          256, 0, stream>>>(qd, kd, vtd, yd);
    out_proj_kernel<<<dim3(5, 64),  256, 0, stream>>>(yd, wouth, bout, out);
}